// Round 6
// baseline (955.028 us; speedup 1.0000x reference)
//
#include <hip/hip_runtime.h>
#include <hip/hip_fp16.h>

// Sinkhorn OT: n=m=4096, d=32, reg=0.1, 100 iterations, uniform marginals.
// R6 = R5 (fp16 K/K^T streaming passes + exact bitwise freeze detection)
//    + Aitken extrapolation on v at fixed iterations to reach the fp16
//      fixpoint in ~half the iterations. The iteration map is contractive
//      and homogeneous deg-1, so relative deltas are scale-clean and any
//      extrapolation misfire self-heals; the freeze skip stays bit-exact.

#define NN 4096
#define MM 4096
#define DD 32
#define N_ITERS 100

static constexpr float INV_REG = 10.0f;
static constexpr float A_MARG  = 1.0f / 4096.0f;
static constexpr float B_MARG  = 1.0f / 4096.0f;

typedef _Float16 h2_t __attribute__((ext_vector_type(2)));

static __device__ __forceinline__ float dot2(unsigned a, unsigned b, float acc) {
#if __has_builtin(__builtin_amdgcn_fdot2)
    return __builtin_amdgcn_fdot2(__builtin_bit_cast(h2_t, a),
                                  __builtin_bit_cast(h2_t, b), acc, false);
#else
    float2 fa = __half22float2(*(const __half2*)&a);
    float2 fb = __half22float2(*(const __half2*)&b);
    acc = fmaf(fa.x, fb.x, acc);
    return fmaf(fa.y, fb.y, acc);
#endif
}

static __device__ __forceinline__ unsigned ld_dev_u32(const unsigned* p) {
    return __hip_atomic_load(p, __ATOMIC_RELAXED, __HIP_MEMORY_SCOPE_AGENT);
}
static __device__ __forceinline__ void st_dev_u32(unsigned* p, unsigned v) {
    __hip_atomic_store(p, v, __ATOMIC_RELAXED, __HIP_MEMORY_SCOPE_AGENT);
}
static __device__ __forceinline__ unsigned short ld_dev_u16(const unsigned short* p) {
    return __hip_atomic_load(p, __ATOMIC_RELAXED, __HIP_MEMORY_SCOPE_AGENT);
}
static __device__ __forceinline__ void st_dev_u16(unsigned short* p, unsigned short v) {
    __hip_atomic_store(p, v, __ATOMIC_RELAXED, __HIP_MEMORY_SCOPE_AGENT);
}

// ---------------------------------------------------------------------------
// Kh[i][j] = (half)exp(-||p_i - q_j||^2 / reg). prime!=0: v16=1/4096,
// v32=1/4096, conv=0, slot=1.
// grid: (4096/256, 4096/16), block 256
// ---------------------------------------------------------------------------
__global__ void compute_K_half(const float* __restrict__ p, const float* __restrict__ q,
                               __half* __restrict__ Kh, __half* __restrict__ v16,
                               float* __restrict__ v32,
                               unsigned* __restrict__ conv, unsigned* __restrict__ slot,
                               int prime) {
    const int tid = threadIdx.x;
    const int j   = blockIdx.x * 256 + tid;
    const int r0  = blockIdx.y * 16;

    if (prime && blockIdx.y == 0) {
        v16[j] = __float2half(B_MARG);
        v32[j] = B_MARG;
        if (blockIdx.x == 0 && tid == 0) { *conv = 0u; *slot = 1u; }
    }

    float qv[DD];
    const float4* q4 = (const float4*)(q + (size_t)j * DD);
#pragma unroll
    for (int k = 0; k < DD / 4; ++k) {
        float4 t = q4[k];
        qv[4 * k + 0] = t.x; qv[4 * k + 1] = t.y;
        qv[4 * k + 2] = t.z; qv[4 * k + 3] = t.w;
    }

    __shared__ float ps[16 * DD];
    ps[tid]       = p[(size_t)r0 * DD + tid];
    ps[tid + 256] = p[(size_t)r0 * DD + tid + 256];
    __syncthreads();

#pragma unroll 4
    for (int ii = 0; ii < 16; ++ii) {
        float acc = 0.0f;
#pragma unroll
        for (int k = 0; k < DD; ++k) {
            float d = ps[ii * DD + k] - qv[k];
            acc = fmaf(d, d, acc);
        }
        Kh[(size_t)(r0 + ii) * MM + j] = __float2half(__expf(-acc * INV_REG));
    }
}

// ---------------------------------------------------------------------------
// u-pass: u[i] = a / (Kh[i,:] . v16). Even t: slot==0 -> sticky conv, skip.
// Odd t: block 0 zeroes slot for this iteration's v-pass detection.
// ---------------------------------------------------------------------------
__global__ void __launch_bounds__(512)
rowpass_u(const __half* __restrict__ Mat, const __half* __restrict__ w16_in,
          float* __restrict__ w32_out, __half* __restrict__ w16_out,
          unsigned* __restrict__ conv, unsigned* __restrict__ slot, int t) {
    if (ld_dev_u32(conv)) return;
    if ((t & 1) == 0) {
        if (ld_dev_u32(slot) == 0u) {
            if (threadIdx.x == 0) st_dev_u32(conv, 1u);
            return;
        }
    } else {
        if (blockIdx.x == 0 && threadIdx.x == 0) st_dev_u32(slot, 0u);
    }

    __shared__ __align__(16) __half vlds[MM];
    const int tid = threadIdx.x;
    ((uint4*)vlds)[tid] = ((const uint4*)w16_in)[tid];
    __syncthreads();

    const int lane = tid & 63;
    const int i    = blockIdx.x * 8 + (tid >> 6);
    const uint4* Mrow = (const uint4*)(Mat + (size_t)i * MM);
    const uint4* V    = (const uint4*)vlds;

    float acc = 0.0f;
#pragma unroll
    for (int c = 0; c < 8; ++c) {
        const int g = c * 64 + lane;
        uint4 kk = Mrow[g];
        uint4 vv = V[g];
        acc = dot2(kk.x, vv.x, acc);
        acc = dot2(kk.y, vv.y, acc);
        acc = dot2(kk.z, vv.z, acc);
        acc = dot2(kk.w, vv.w, acc);
    }
#pragma unroll
    for (int off = 32; off > 0; off >>= 1) acc += __shfl_down(acc, off, 64);
    if (lane == 0) {
        float r = A_MARG / acc;
        w32_out[i] = r;
        w16_out[i] = __float2half(r);
    }
}

// ---------------------------------------------------------------------------
// v-pass: v[j] = b / (KTh[j,:] . u16); writes v32, v16, and ring[t%3].
// Odd t: bitwise-compare vs hist (v from t-2); mismatch -> slot=1.
// ---------------------------------------------------------------------------
__global__ void __launch_bounds__(512)
rowpass_v(const __half* __restrict__ Mat, const __half* __restrict__ w16_in,
          float* __restrict__ w32_out, __half* __restrict__ w16_out,
          float* __restrict__ ring_t,
          unsigned short* __restrict__ hist,
          unsigned* __restrict__ conv, unsigned* __restrict__ slot, int t) {
    if (ld_dev_u32(conv)) return;

    __shared__ __align__(16) __half vlds[MM];
    const int tid = threadIdx.x;
    ((uint4*)vlds)[tid] = ((const uint4*)w16_in)[tid];
    __syncthreads();

    const int lane = tid & 63;
    const int i    = blockIdx.x * 8 + (tid >> 6);
    const uint4* Mrow = (const uint4*)(Mat + (size_t)i * MM);
    const uint4* V    = (const uint4*)vlds;

    float acc = 0.0f;
#pragma unroll
    for (int c = 0; c < 8; ++c) {
        const int g = c * 64 + lane;
        uint4 kk = Mrow[g];
        uint4 vv = V[g];
        acc = dot2(kk.x, vv.x, acc);
        acc = dot2(kk.y, vv.y, acc);
        acc = dot2(kk.z, vv.z, acc);
        acc = dot2(kk.w, vv.w, acc);
    }
#pragma unroll
    for (int off = 32; off > 0; off >>= 1) acc += __shfl_down(acc, off, 64);
    if (lane == 0) {
        float r = B_MARG / acc;
        w32_out[i] = r;
        ring_t[i]  = r;
        const __half h = __float2half(r);
        const unsigned short bits = __half_as_ushort(h);
        if (t & 1) {
            unsigned short old2 = ld_dev_u16(hist + i);
            if (old2 != bits) st_dev_u32(slot, 1u);
            st_dev_u16(hist + i, bits);
        }
        w16_out[i] = h;
    }
}

// ---------------------------------------------------------------------------
// Aitken extrapolation: Delta = v_t/v_{t-1}-1, delta = v_{t-1}/v_{t-2}-1,
// lambda = <Delta,delta>/<delta,delta> clamped [0,0.9];
// v <- v_t * clamp(1 + Delta*lambda/(1-lambda), 0.05, 20).
// Single block, 1024 threads, 4 elems each. Self-healing on misfire.
// ---------------------------------------------------------------------------
__global__ void __launch_bounds__(1024)
extrap_v(float* __restrict__ v32, __half* __restrict__ v16,
         float* __restrict__ r0, const float* __restrict__ r1,
         const float* __restrict__ r2, const unsigned* __restrict__ conv) {
    if (ld_dev_u32(conv)) return;

    __shared__ float s_num[16], s_den[16];
    const int tid  = threadIdx.x;
    const int wave = tid >> 6, lane = tid & 63;

    float vt[4], Dl[4];
    float num = 0.f, den = 0.f;
#pragma unroll
    for (int k = 0; k < 4; ++k) {
        const int i = tid * 4 + k;
        const float a = r0[i], bm = r1[i], c = r2[i];
        vt[k] = a;
        const float D = a / bm - 1.0f;
        const float d = bm / c - 1.0f;
        Dl[k] = D;
        num += D * d;
        den += d * d;
    }
#pragma unroll
    for (int off = 32; off > 0; off >>= 1) {
        num += __shfl_down(num, off, 64);
        den += __shfl_down(den, off, 64);
    }
    if (lane == 0) { s_num[wave] = num; s_den[wave] = den; }
    __syncthreads();
    float tn = 0.f, td = 0.f;
#pragma unroll
    for (int q = 0; q < 16; ++q) { tn += s_num[q]; td += s_den[q]; }

    if (td < 1e-28f) return;                 // deltas ~0: at/near freeze
    float lam = tn / td;
    if (!(lam > 0.0f)) return;               // no coherent decaying mode
    lam = fminf(lam, 0.9f);
    const float f = lam / (1.0f - lam);

#pragma unroll
    for (int k = 0; k < 4; ++k) {
        const int i = tid * 4 + k;
        float g = 1.0f + Dl[k] * f;
        g = fminf(fmaxf(g, 0.05f), 20.0f);
        const float nv = vt[k] * g;
        v32[i] = nv;
        r0[i]  = nv;                         // keep ring consistent w/ traj
        v16[i] = __float2half(nv);
    }
}

// ---------------------------------------------------------------------------
// gamma[i][j] = u[i] * exp(-||x_i-y_j||^2/reg) * v[j]   (exact fp32 K)
// grid: (16, 256), block 256
// ---------------------------------------------------------------------------
__global__ void epilogue(const float* __restrict__ x, const float* __restrict__ y,
                         const float* __restrict__ u, const float* __restrict__ v,
                         float* __restrict__ out) {
    const int tid = threadIdx.x;
    const int j   = blockIdx.x * 256 + tid;
    const int r0  = blockIdx.y * 16;

    float yv[DD];
    const float4* y4 = (const float4*)(y + (size_t)j * DD);
#pragma unroll
    for (int k = 0; k < DD / 4; ++k) {
        float4 t = y4[k];
        yv[4 * k + 0] = t.x; yv[4 * k + 1] = t.y;
        yv[4 * k + 2] = t.z; yv[4 * k + 3] = t.w;
    }

    __shared__ float xs[16 * DD];
    __shared__ float u_lds[16];
    xs[tid]       = x[(size_t)r0 * DD + tid];
    xs[tid + 256] = x[(size_t)r0 * DD + tid + 256];
    if (tid < 16) u_lds[tid] = u[r0 + tid];
    __syncthreads();

    const float vj = v[j];
#pragma unroll 4
    for (int ii = 0; ii < 16; ++ii) {
        float acc = 0.0f;
#pragma unroll
        for (int k = 0; k < DD; ++k) {
            float d = xs[ii * DD + k] - yv[k];
            acc = fmaf(d, d, acc);
        }
        out[(size_t)(r0 + ii) * MM + j] = u_lds[ii] * __expf(-acc * INV_REG) * vj;
    }
}

extern "C" void kernel_launch(void* const* d_in, const int* in_sizes, int n_in,
                              void* d_out, int out_size, void* d_ws, size_t ws_size,
                              hipStream_t stream) {
    const float* x = (const float*)d_in[0];
    const float* y = (const float*)d_in[1];
    __half*   Kh   = (__half*)d_ws;                    // 32 MB
    __half*   KTh  = Kh + (size_t)NN * MM;             // 32 MB
    float*    u32  = (float*)(KTh + (size_t)NN * MM);  // 16 KB
    float*    v32  = u32 + NN;                         // 16 KB
    __half*   u16  = (__half*)(v32 + MM);              // 8 KB
    __half*   v16  = u16 + NN;                         // 8 KB
    unsigned short* hist = (unsigned short*)(v16 + MM);// 8 KB (0xAA-safe init)
    float*    ring = (float*)(hist + MM);              // 3 x 16 KB
    unsigned* conv = (unsigned*)(ring + 3 * MM);       // 4 B
    unsigned* slot = conv + 1;                         // 4 B
    float*    out  = (float*)d_out;

    compute_K_half<<<dim3(MM / 256, NN / 16), 256, 0, stream>>>(x, y, Kh, v16, v32, conv, slot, 1);
    compute_K_half<<<dim3(NN / 256, MM / 16), 256, 0, stream>>>(y, x, KTh, v16, v32, conv, slot, 0);

    for (int t = 0; t < N_ITERS; ++t) {
        rowpass_u<<<NN / 8, 512, 0, stream>>>(Kh, v16, u32, u16, conv, slot, t);
        rowpass_v<<<MM / 8, 512, 0, stream>>>(KTh, u16, v32, v16,
                                              ring + (size_t)(t % 3) * MM,
                                              hist, conv, slot, t);
        if (t >= 8 && t <= 44 && (t - 8) % 6 == 0) {  // t = 8,14,20,26,32,38,44
            extrap_v<<<1, 1024, 0, stream>>>(v32, v16,
                                             ring + (size_t)(t % 3) * MM,
                                             ring + (size_t)((t + 2) % 3) * MM,
                                             ring + (size_t)((t + 1) % 3) * MM,
                                             conv);
        }
    }

    epilogue<<<dim3(MM / 256, NN / 16), 256, 0, stream>>>(x, y, u32, v32, out);
}